// Round 7
// baseline (134.442 us; speedup 1.0000x reference)
//
#include <hip/hip_runtime.h>
#include <stdint.h>

#define Bb 2
#define Ll 2048
#define Dd 1024
#define Hh 16
#define DKd 64
#define Mm (Bb*Ll)   // 4096

typedef __bf16 bf16_t;
typedef __bf16 bf16x8 __attribute__((ext_vector_type(8)));
typedef float f32x4 __attribute__((ext_vector_type(4)));
typedef unsigned u32x2 __attribute__((ext_vector_type(2)));

#define AS1C(p) ((const __attribute__((address_space(1))) void*)(p))
#define AS3(p)  ((__attribute__((address_space(3))) void*)(p))

__device__ __forceinline__ unsigned short bfu(float f){
  return __builtin_bit_cast(unsigned short, (bf16_t)f);   // native v_cvt, RTNE
}
__device__ __forceinline__ void wait_vm2(){ asm volatile("s_waitcnt vmcnt(2)" ::: "memory"); }
__device__ __forceinline__ void wait_vm8(){ asm volatile("s_waitcnt vmcnt(8)" ::: "memory"); }
__device__ __forceinline__ void wait_vm0(){ asm volatile("s_waitcnt vmcnt(0)" ::: "memory"); }
__device__ __forceinline__ void bar(){
  __builtin_amdgcn_sched_barrier(0);
  __builtin_amdgcn_s_barrier();
  __builtin_amdgcn_sched_barrier(0);
}

// ---------------- fp32 -> bf16 convert (multi-buffer, one launch) ----------------
struct CvtArgs { const float* in[4]; ushort4* out[4]; };

__global__ void cvt_multi(CvtArgs a, int n4){
  const int z = blockIdx.y;
  const float* in = a.in[z];
  ushort4* out = a.out[z];
  int i = blockIdx.x*256 + threadIdx.x;
  if (i < n4){
    float4 v = ((const float4*)in)[i];
    ushort4 o; o.x=bfu(v.x); o.y=bfu(v.y); o.z=bfu(v.z); o.w=bfu(v.w);
    out[i] = o;
  }
}

// ---------------- per-head transpose: Vh[bh][l][dk] -> VT[bh][dk][l] ----------------
__global__ __launch_bounds__(256) void transpose_v(const bf16_t* __restrict__ Vh,
                                                   bf16_t* __restrict__ VT){
  __shared__ bf16_t Tl[64][72];
  const int bh = blockIdx.y;
  const int l0 = blockIdx.x * 64;
  const int tid = threadIdx.x;
  const bf16_t* src = Vh + (size_t)bh*Ll*DKd;
  bf16_t* dst = VT + (size_t)bh*Ll*DKd;
#pragma unroll
  for (int rd = 0; rd < 2; ++rd){
    int l = rd*32 + (tid>>3), dk0 = (tid&7)*8;
    bf16x8 v = *(const bf16x8*)(src + (size_t)(l0+l)*DKd + dk0);
#pragma unroll
    for (int j = 0; j < 8; ++j) Tl[dk0+j][l] = v[j];
  }
  __syncthreads();
#pragma unroll
  for (int rd = 0; rd < 2; ++rd){
    int dk = rd*32 + (tid>>3), lc = (tid&7)*8;
    *(bf16x8*)(dst + (size_t)dk*Ll + l0 + lc) = *(const bf16x8*)&Tl[dk][lc];
  }
}

// ---------------- GEMM: C = A(MxK) * B(NxK)^T + bias, 128x128 counted-vmcnt ----------------
#define BM 128
#define BN 128
#define BKs 64

struct GemmArgs {
  const bf16_t* A[3];
  const bf16_t* W[3];
  const float*  bias[3];
  void*         out[3];
  float         scale[3];
};

__device__ __forceinline__ void stage_tile(
    const bf16_t* __restrict__ A, const bf16_t* __restrict__ Bw,
    int m0, int n0, int K, int k0, bf16_t* As, bf16_t* Bs,
    int w, int srow, int scol)
{
#pragma unroll
  for (int i = 0; i < 4; i++) {
    int c = i*4 + w;
    int row = c*8 + srow;
    int sc = scol ^ ((row & 7) << 3);   // inverse-swizzled global source
    __builtin_amdgcn_global_load_lds(AS1C(A + (size_t)(m0+row)*K + k0 + sc),
                                     AS3(As + c*512), 16, 0, 0);
  }
#pragma unroll
  for (int i = 0; i < 4; i++) {
    int c = i*4 + w;
    int row = c*8 + srow;
    int sc = scol ^ ((row & 7) << 3);
    __builtin_amdgcn_global_load_lds(AS1C(Bw + (size_t)(n0+row)*K + k0 + sc),
                                     AS3(Bs + c*512), 16, 0, 0);
  }
}

template<int OUTMODE>
__global__ __launch_bounds__(256) void gemm_bt(GemmArgs ga, int M, int N, int K)
{
  const int z = blockIdx.z;
  const bf16_t* __restrict__ A  = ga.A[z];
  const bf16_t* __restrict__ Bw = ga.W[z];
  const float*  __restrict__ bias = ga.bias[z];
  void* __restrict__ out = ga.out[z];
  const float scale = ga.scale[z];

  __shared__ bf16_t As[2][BM*BKs];   // 2x16KB
  __shared__ bf16_t Bs[2][BN*BKs];   // 2x16KB
  const int tid = threadIdx.x;
  const int lane = tid & 63;
  const int w = tid >> 6;
  const int m0 = blockIdx.x * BM;
  const int n0 = blockIdx.y * BN;
  const int wr = (w >> 1) * 64, wc = (w & 1) * 64;
  const int lrow16 = lane & 15;
  const int kgrp = lane >> 4;
  const int srow = lane >> 3;
  const int scol = (lane & 7) * 8;

  f32x4 acc[4][4] = {};

  stage_tile(A, Bw, m0, n0, K, 0, As[0], Bs[0], w, srow, scol);

  const int KT = K / BKs;
  int cur = 0;
  for (int kt = 0; kt < KT; ++kt) {
    if (kt + 1 < KT) {
      stage_tile(A, Bw, m0, n0, K, (kt+1)*BKs, As[cur^1], Bs[cur^1], w, srow, scol);
      wait_vm8();              // tile kt done; kt+1 stays in flight
    } else {
      wait_vm0();
    }
    bar();                     // staging of [cur] visible to all waves
#pragma unroll
    for (int ks = 0; ks < 2; ++ks) {
      const int kbyte = ks*64 + kgrp*16;
      bf16x8 af[4], bfr[4];
#pragma unroll
      for (int m = 0; m < 4; m++) {
        int row = wr + m*16 + lrow16;
        af[m] = *(const bf16x8*)((const char*)As[cur] + row*128 + (kbyte ^ ((row & 7) << 4)));
      }
#pragma unroll
      for (int n = 0; n < 4; n++) {
        int row = wc + n*16 + lrow16;
        bfr[n] = *(const bf16x8*)((const char*)Bs[cur] + row*128 + (kbyte ^ ((row & 7) << 4)));
      }
#pragma unroll
      for (int m = 0; m < 4; m++)
#pragma unroll
        for (int n = 0; n < 4; n++)
          acc[m][n] = __builtin_amdgcn_mfma_f32_16x16x32_bf16(af[m], bfr[n], acc[m][n], 0, 0, 0);
    }
    bar();                     // all reads of [cur] complete before reuse
    cur ^= 1;
  }

#pragma unroll
  for (int m = 0; m < 4; m++)
#pragma unroll
    for (int n = 0; n < 4; n++)
#pragma unroll
      for (int i = 0; i < 4; i++) {
        int row = m0 + wr + m*16 + kgrp*4 + i;
        int col = n0 + wc + n*16 + lrow16;
        float v = (acc[m][n][i] + bias[col]) * scale;
        if (OUTMODE == 1) {
          ((float*)out)[(size_t)row*N + col] = v;
        } else {
          int b = row >> 11, l = row & 2047;
          int h = col >> 6, dk = col & 63;
          ((unsigned short*)out)[((size_t)((b<<4) + h)*Ll + l)*DKd + dk] = bfu(v);
        }
      }
}

// ---------------- causal flash attention ----------------
// 256 blocks x 8 waves, QBLK=128: pair (T=j, 15-j) run sequentially = uniform
// 34 KV-steps. Counted-vmcnt pipeline, swapped QK^T, in-register softmax,
// l via MFMA vs ones, packed swizzled P->LDS, V^T staged like K.
#define KVB 64

__global__ __launch_bounds__(512) void attn_kernel(
    const bf16_t* __restrict__ Qh, const bf16_t* __restrict__ Kh,
    const bf16_t* __restrict__ VTg, unsigned short* __restrict__ Oa)
{
  const int id = blockIdx.x;                 // 0..255
  const int x = id & 7;                      // XCD pin
  const int rest = id >> 3;                  // 0..31
  const int hq = rest >> 3;                  // 0..3
  const int j  = rest & 7;                   // pair: q-tiles j and 15-j (128 rows each)
  const int bh = x + 8*hq;
  const int qtA = j, qtB = 15 - j;

  const int tid = threadIdx.x, lane = tid & 63, w = tid >> 6;   // w 0..7
  const int r = lane & 15, g = lane >> 4;

  const bf16_t* Qp  = Qh  + (size_t)bh * Ll * DKd;
  const bf16_t* Kp  = Kh  + (size_t)bh * Ll * DKd;
  const bf16_t* VTp = VTg + (size_t)bh * Ll * DKd;   // [dk][l]

  __shared__ bf16_t Klds[2][64*64];   // 16KB, XOR-swizzled 128B rows
  __shared__ bf16_t Vlds[2][64*64];   // 16KB, V^T rows (dk), same swizzle
  __shared__ bf16_t Plds[8][16*64];   // 16KB, per-wave P rows (q), swizzled

  // Q fragments for both phases
  bf16x8 qf[2], qB[2];
#pragma unroll
  for (int ks = 0; ks < 2; ++ks) {
    qf[ks] = *(const bf16x8*)(Qp + (size_t)(qtA*128 + w*16 + r)*DKd + ks*32 + g*8);
    qB[ks] = *(const bf16x8*)(Qp + (size_t)(qtB*128 + w*16 + r)*DKd + ks*32 + g*8);
  }
  int qb = qtA*128 + w*16;

  bf16x8 ones;
#pragma unroll
  for (int jj = 0; jj < 8; ++jj) ones[jj] = (bf16_t)1.0f;

  f32x4 accO[4] = {};
  f32x4 accL = {};
  float mrow = -1e30f;

  // staging lane constants (each wave stages ONE K-chunk + ONE V-chunk of 8 rows)
  const int krow_l = lane >> 3;                        // 0..7
  const int kcol_l = ((lane & 7)*16) ^ (krow_l << 4);  // swizzled source byte
  char* Pw = (char*)&Plds[w][0];
  const int rsw = (r & 7) << 4;
  const int b_ = bh >> 4, h_ = bh & 15;
  const int sA = 2*j + 1;                              // last step of phase A

  auto pre_tiles = [&](int kv, int buf){
    __builtin_amdgcn_global_load_lds(
      AS1C((const char*)Kp + (size_t)(kv*KVB + w*8 + krow_l)*128 + kcol_l),
      AS3((char*)&Klds[buf][0] + w*1024), 16, 0, 0);
    __builtin_amdgcn_global_load_lds(
      AS1C((const char*)VTp + (size_t)(w*8 + krow_l)*4096 + kv*128 + kcol_l),
      AS3((char*)&Vlds[buf][0] + w*1024), 16, 0, 0);
  };

  pre_tiles(0, 0);   // phase A kv=0

  int cur = 0;
  for (int s = 0; s < 34; ++s) {
    if (s < 33) {
      int kv2 = (s < sA) ? s + 1 : s - sA;   // next step's kv (phase B restarts at 0)
      pre_tiles(kv2, cur^1);
      wait_vm2();                            // this step's chunks done; next in flight
    } else {
      wait_vm0();
    }
    bar();                                   // staging of [cur] visible to all waves

    const int kv0 = ((s <= sA) ? s : s - sA - 1) * KVB;

    // S^T = K Q^T : sv[n][i] = S[q=qb+r][kv = kv0 + n*16 + g*4 + i]
    const char* Kbase = (const char*)&Klds[cur][0];
    f32x4 sv[4] = {};
    __builtin_amdgcn_s_setprio(1);
#pragma unroll
    for (int ks = 0; ks < 2; ++ks) {
      const int kbyte = ks*64 + g*16;
#pragma unroll
      for (int n = 0; n < 4; ++n) {
        int row = n*16 + r;
        bf16x8 kf = *(const bf16x8*)(Kbase + row*128 + (kbyte ^ ((row & 7) << 4)));
        sv[n] = __builtin_amdgcn_mfma_f32_16x16x32_bf16(kf, qf[ks], sv[n], 0, 0, 0);
      }
    }
    __builtin_amdgcn_s_setprio(0);

    // causal mask: the last two steps of each phase touch the diagonal
    if (s >= sA - 1) {
      if (s <= sA || s >= 32) {
        const int qg = qb + r;
#pragma unroll
        for (int n = 0; n < 4; ++n)
#pragma unroll
          for (int i = 0; i < 4; ++i)
            if (kv0 + n*16 + g*4 + i > qg) sv[n][i] = -1e30f;
      }
    }

    // in-register online softmax (log2 domain, defer-max)
    float m0 = fmaxf(fmaxf(sv[0][0], sv[0][1]), sv[0][2]);
    float m1 = fmaxf(fmaxf(sv[0][3], sv[1][0]), sv[1][1]);
    float m2 = fmaxf(fmaxf(sv[1][2], sv[1][3]), sv[2][0]);
    float m3 = fmaxf(fmaxf(sv[2][1], sv[2][2]), sv[2][3]);
    float m4 = fmaxf(fmaxf(sv[3][0], sv[3][1]), sv[3][2]);
    float mx = fmaxf(fmaxf(fmaxf(m0, m1), m2), fmaxf(fmaxf(m3, m4), sv[3][3]));
    if (__any(mx > mrow + 8.f)) {
      mx = fmaxf(mx, __shfl_xor(mx, 16));
      mx = fmaxf(mx, __shfl_xor(mx, 32));
      float mnew = fmaxf(mrow, mx);
      float corr = __builtin_amdgcn_exp2f(mrow - mnew);
      float c0 = __shfl(corr, g*4 + 0);
      float c1 = __shfl(corr, g*4 + 1);
      float c2 = __shfl(corr, g*4 + 2);
      float c3 = __shfl(corr, g*4 + 3);
#pragma unroll
      for (int n = 0; n < 4; ++n) {
        accO[n][0] *= c0; accO[n][1] *= c1; accO[n][2] *= c2; accO[n][3] *= c3;
      }
      accL[0] *= c0; accL[1] *= c1; accL[2] *= c2; accL[3] *= c3;
      mrow = mnew;
    }
#pragma unroll
    for (int n = 0; n < 4; ++n)
#pragma unroll
      for (int i = 0; i < 4; ++i)
        sv[n][i] = __builtin_amdgcn_exp2f(sv[n][i] - mrow);

    // pack P -> per-wave LDS: 4 x b64 swizzled writes
#pragma unroll
    for (int n = 0; n < 4; ++n) {
      unsigned lo = (unsigned)bfu(sv[n][0]) | ((unsigned)bfu(sv[n][1]) << 16);
      unsigned hi = (unsigned)bfu(sv[n][2]) | ((unsigned)bfu(sv[n][3]) << 16);
      u32x2 pk; pk[0] = lo; pk[1] = hi;
      *(u32x2*)(Pw + r*128 + ((n*32 + g*8) ^ rsw)) = pk;
    }

    // PV: O += P * V, l += P * 1
    const char* Vbase = (const char*)&Vlds[cur][0];
    __builtin_amdgcn_s_setprio(1);
#pragma unroll
    for (int ks = 0; ks < 2; ++ks) {
      const int kbyte = ks*64 + g*16;
      bf16x8 pa = *(const bf16x8*)(Pw + r*128 + (kbyte ^ rsw));
      accL = __builtin_amdgcn_mfma_f32_16x16x32_bf16(pa, ones, accL, 0, 0, 0);
#pragma unroll
      for (int n = 0; n < 4; ++n) {
        int row = n*16 + r;
        bf16x8 vf = *(const bf16x8*)(Vbase + row*128 + (kbyte ^ ((row & 7) << 4)));
        accO[n] = __builtin_amdgcn_mfma_f32_16x16x32_bf16(pa, vf, accO[n], 0, 0, 0);
      }
    }
    __builtin_amdgcn_s_setprio(0);

    // phase A finished: store, reset, switch Q
    if (s == sA) {
#pragma unroll
      for (int i = 0; i < 4; ++i) {
        float inv = 1.f / accL[i];
        int q = qb + g*4 + i;
#pragma unroll
        for (int n = 0; n < 4; ++n)
          Oa[((size_t)(b_*Ll + q))*Dd + h_*DKd + n*16 + r] = bfu(accO[n][i] * inv);
      }
#pragma unroll
      for (int n = 0; n < 4; ++n) accO[n] = f32x4{};
      accL = f32x4{};
      mrow = -1e30f;
      qf[0] = qB[0]; qf[1] = qB[1];
      qb = qtB*128 + w*16;
    }

    bar();                                   // all reads of [cur] done before reuse
    cur ^= 1;
  }

  // phase B store
#pragma unroll
  for (int i = 0; i < 4; ++i) {
    float inv = 1.f / accL[i];
    int q = qb + g*4 + i;
#pragma unroll
    for (int n = 0; n < 4; ++n)
      Oa[((size_t)(b_*Ll + q))*Dd + h_*DKd + n*16 + r] = bfu(accO[n][i] * inv);
  }
}

// ---------------- launch ----------------
extern "C" void kernel_launch(void* const* d_in, const int* in_sizes, int n_in,
                              void* d_out, int out_size, void* d_ws, size_t ws_size,
                              hipStream_t stream)
{
  const float* q  = (const float*)d_in[0];
  const float* k  = (const float*)d_in[1];
  const float* v  = (const float*)d_in[2];
  // d_in[3] = mask (causal, hardcoded)
  const float* wq = (const float*)d_in[4];
  const float* bq = (const float*)d_in[5];
  const float* wk = (const float*)d_in[6];
  const float* bk = (const float*)d_in[7];
  const float* wv = (const float*)d_in[8];
  const float* bv = (const float*)d_in[9];
  const float* wo = (const float*)d_in[10];
  const float* bo = (const float*)d_in[11];

  char* ws = (char*)d_ws;
  bf16_t* Xq = (bf16_t*)(ws + 0);          // dead after Q-GEMM; reused as VT
  bf16_t* Xk = (bf16_t*)(ws + 8388608);
  bf16_t* Xv = (bf16_t*)(ws + 16777216);
  bf16_t* Wq = (bf16_t*)(ws + 25165824);
  bf16_t* Wk = (bf16_t*)(ws + 27262976);
  bf16_t* Wv = (bf16_t*)(ws + 29360128);
  bf16_t* Wo = (bf16_t*)(ws + 31457280);
  bf16_t* Qh = (bf16_t*)(ws + 33554432);
  bf16_t* Kh = (bf16_t*)(ws + 41943040);
  bf16_t* Vh = (bf16_t*)(ws + 50331648);
  bf16_t* Oa = (bf16_t*)(ws + 58720256);   // total 64 MiB
  bf16_t* VT = Xq;                          // [bh][dk][l], 8MB

  const int NX = Mm * Dd;   // 4194304
  const int NW = Dd * Dd;   // 1048576

  CvtArgs cx; cx.in[0]=q; cx.in[1]=k; cx.in[2]=v; cx.in[3]=q;
  cx.out[0]=(ushort4*)Xq; cx.out[1]=(ushort4*)Xk; cx.out[2]=(ushort4*)Xv; cx.out[3]=(ushort4*)Xq;
  cvt_multi<<<dim3(NX/4/256, 3), 256, 0, stream>>>(cx, NX/4);

  CvtArgs cw; cw.in[0]=wq; cw.in[1]=wk; cw.in[2]=wv; cw.in[3]=wo;
  cw.out[0]=(ushort4*)Wq; cw.out[1]=(ushort4*)Wk; cw.out[2]=(ushort4*)Wv; cw.out[3]=(ushort4*)Wo;
  cvt_multi<<<dim3(NW/4/256, 4), 256, 0, stream>>>(cw, NW/4);

  const float qscale = 0.125f * 1.4426950408889634f;  // 1/sqrt(DK) * log2(e)
  GemmArgs gqkv;
  gqkv.A[0]=Xq; gqkv.A[1]=Xk; gqkv.A[2]=Xv;
  gqkv.W[0]=Wq; gqkv.W[1]=Wk; gqkv.W[2]=Wv;
  gqkv.bias[0]=bq; gqkv.bias[1]=bk; gqkv.bias[2]=bv;
  gqkv.out[0]=Qh; gqkv.out[1]=Kh; gqkv.out[2]=Vh;
  gqkv.scale[0]=qscale; gqkv.scale[1]=1.0f; gqkv.scale[2]=1.0f;
  gemm_bt<0><<<dim3(Mm/BM, Dd/BN, 3), 256, 0, stream>>>(gqkv, Mm, Dd, Dd);

  transpose_v<<<dim3(32, 32), 256, 0, stream>>>(Vh, VT);

  attn_kernel<<<dim3(256), 512, 0, stream>>>(Qh, Kh, VT, (unsigned short*)Oa);

  GemmArgs go;
  go.A[0]=Oa; go.A[1]=Oa; go.A[2]=Oa;
  go.W[0]=Wo; go.W[1]=Wo; go.W[2]=Wo;
  go.bias[0]=bo; go.bias[1]=bo; go.bias[2]=bo;
  go.out[0]=d_out; go.out[1]=d_out; go.out[2]=d_out;
  go.scale[0]=1.0f; go.scale[1]=1.0f; go.scale[2]=1.0f;
  gemm_bt<1><<<dim3(Mm/BM, Dd/BN, 1), 256, 0, stream>>>(go, Mm, Dd, Dd);
}

// Round 8
// 129.670 us; speedup vs baseline: 1.0368x; 1.0368x over previous
//
#include <hip/hip_runtime.h>
#include <stdint.h>

#define Bb 2
#define Ll 2048
#define Dd 1024
#define Hh 16
#define DKd 64
#define Mm (Bb*Ll)   // 4096

typedef __bf16 bf16_t;
typedef __bf16 bf16x8 __attribute__((ext_vector_type(8)));
typedef float f32x4 __attribute__((ext_vector_type(4)));
typedef unsigned u32x2 __attribute__((ext_vector_type(2)));

#define AS1C(p) ((const __attribute__((address_space(1))) void*)(p))
#define AS3(p)  ((__attribute__((address_space(3))) void*)(p))

__device__ __forceinline__ unsigned short bfu(float f){
  return __builtin_bit_cast(unsigned short, (bf16_t)f);   // native v_cvt, RTNE
}
__device__ __forceinline__ void wait_vm6(){ asm volatile("s_waitcnt vmcnt(6)" ::: "memory"); }
__device__ __forceinline__ void wait_vm8(){ asm volatile("s_waitcnt vmcnt(8)" ::: "memory"); }
__device__ __forceinline__ void wait_vm0(){ asm volatile("s_waitcnt vmcnt(0)" ::: "memory"); }
__device__ __forceinline__ void bar(){
  __builtin_amdgcn_sched_barrier(0);
  __builtin_amdgcn_s_barrier();
  __builtin_amdgcn_sched_barrier(0);
}

// ---------------- fp32 -> bf16 convert: all 7 buffers, one launch ----------------
struct Cvt7 { const float* in[7]; ushort4* out[7]; int n4[7]; };

__global__ void cvt_multi(Cvt7 a){
  const int z = blockIdx.y;
  int i = blockIdx.x*256 + threadIdx.x;
  if (i < a.n4[z]){
    float4 v = ((const float4*)a.in[z])[i];
    ushort4 o; o.x=bfu(v.x); o.y=bfu(v.y); o.z=bfu(v.z); o.w=bfu(v.w);
    a.out[z][i] = o;
  }
}

// ---------------- per-head transpose: Vh[bh][l][dk] -> VT[bh][dk][l] ----------------
__global__ __launch_bounds__(256) void transpose_v(const bf16_t* __restrict__ Vh,
                                                   bf16_t* __restrict__ VT){
  __shared__ bf16_t Tl[64][72];
  const int bh = blockIdx.y;
  const int l0 = blockIdx.x * 64;
  const int tid = threadIdx.x;
  const bf16_t* src = Vh + (size_t)bh*Ll*DKd;
  bf16_t* dst = VT + (size_t)bh*Ll*DKd;
#pragma unroll
  for (int rd = 0; rd < 2; ++rd){
    int l = rd*32 + (tid>>3), dk0 = (tid&7)*8;
    bf16x8 v = *(const bf16x8*)(src + (size_t)(l0+l)*DKd + dk0);
#pragma unroll
    for (int j = 0; j < 8; ++j) Tl[dk0+j][l] = v[j];
  }
  __syncthreads();
#pragma unroll
  for (int rd = 0; rd < 2; ++rd){
    int dk = rd*32 + (tid>>3), lc = (tid&7)*8;
    *(bf16x8*)(dst + (size_t)dk*Ll + l0 + lc) = *(const bf16x8*)&Tl[dk][lc];
  }
}

// ---------------- GEMM: C = A(MxK) * B(NxK)^T + bias (round-6 verified) ----------------
#define BM 128
#define BN 64
#define BKs 64

struct GemmArgs {
  const bf16_t* A[3];
  const bf16_t* W[3];
  const float*  bias[3];
  void*         out[3];
  float         scale[3];
};

__device__ __forceinline__ void stage_tile(
    const bf16_t* __restrict__ A, const bf16_t* __restrict__ Bw,
    int m0, int n0, int K, int k0, bf16_t* As, bf16_t* Bs,
    int w, int srow, int scol)
{
#pragma unroll
  for (int i = 0; i < 4; i++) {
    int c = i*4 + w;
    int row = c*8 + srow;
    int sc = scol ^ ((row & 7) << 3);   // inverse-swizzled global source
    __builtin_amdgcn_global_load_lds(AS1C(A + (size_t)(m0+row)*K + k0 + sc),
                                     AS3(As + c*512), 16, 0, 0);
  }
#pragma unroll
  for (int i = 0; i < 2; i++) {
    int c = i*4 + w;
    int row = c*8 + srow;
    int sc = scol ^ ((row & 7) << 3);
    __builtin_amdgcn_global_load_lds(AS1C(Bw + (size_t)(n0+row)*K + k0 + sc),
                                     AS3(Bs + c*512), 16, 0, 0);
  }
}

template<int OUTMODE>
__global__ __launch_bounds__(256) void gemm_bt(GemmArgs ga, int M, int N, int K)
{
  const int z = blockIdx.z;
  const bf16_t* __restrict__ A  = ga.A[z];
  const bf16_t* __restrict__ Bw = ga.W[z];
  const float*  __restrict__ bias = ga.bias[z];
  void* __restrict__ out = ga.out[z];
  const float scale = ga.scale[z];

  __shared__ bf16_t As[2][BM*BKs];   // 2x16KB
  __shared__ bf16_t Bs[2][BN*BKs];   // 2x8KB
  const int tid = threadIdx.x;
  const int lane = tid & 63;
  const int w = tid >> 6;
  const int m0 = blockIdx.x * BM;
  const int n0 = blockIdx.y * BN;
  const int wr = (w >> 1) * 64, wc = (w & 1) * 32;
  const int lrow16 = lane & 15;
  const int kgrp = lane >> 4;
  const int srow = lane >> 3;
  const int scol = (lane & 7) * 8;

  f32x4 acc[4][2] = {};

  stage_tile(A, Bw, m0, n0, K, 0, As[0], Bs[0], w, srow, scol);

  const int KT = K / BKs;
  int cur = 0;
  for (int kt = 0; kt < KT; ++kt) {
    if (kt + 1 < KT) {
      stage_tile(A, Bw, m0, n0, K, (kt+1)*BKs, As[cur^1], Bs[cur^1], w, srow, scol);
      wait_vm6();              // tile kt done; kt+1 stays in flight
    } else {
      wait_vm0();
    }
    bar();                     // staging of [cur] visible to all waves
#pragma unroll
    for (int ks = 0; ks < 2; ++ks) {
      const int kbyte = ks*64 + kgrp*16;
      bf16x8 af[4], bfr[2];
#pragma unroll
      for (int m = 0; m < 4; m++) {
        int row = wr + m*16 + lrow16;
        af[m] = *(const bf16x8*)((const char*)As[cur] + row*128 + (kbyte ^ ((row & 7) << 4)));
      }
#pragma unroll
      for (int n = 0; n < 2; n++) {
        int row = wc + n*16 + lrow16;
        bfr[n] = *(const bf16x8*)((const char*)Bs[cur] + row*128 + (kbyte ^ ((row & 7) << 4)));
      }
#pragma unroll
      for (int m = 0; m < 4; m++)
#pragma unroll
        for (int n = 0; n < 2; n++)
          acc[m][n] = __builtin_amdgcn_mfma_f32_16x16x32_bf16(af[m], bfr[n], acc[m][n], 0, 0, 0);
    }
    bar();                     // all reads of [cur] complete before reuse
    cur ^= 1;
  }

#pragma unroll
  for (int m = 0; m < 4; m++)
#pragma unroll
    for (int n = 0; n < 2; n++)
#pragma unroll
      for (int i = 0; i < 4; i++) {
        int row = m0 + wr + m*16 + kgrp*4 + i;
        int col = n0 + wc + n*16 + lrow16;
        float v = (acc[m][n][i] + bias[col]) * scale;
        if (OUTMODE == 1) {
          ((float*)out)[(size_t)row*N + col] = v;
        } else {
          int b = row >> 11, l = row & 2047;
          int h = col >> 6, dk = col & 63;
          ((unsigned short*)out)[((size_t)((b<<4) + h)*Ll + l)*DKd + dk] = bfu(v);
        }
      }
}

// ---------------- causal flash attention ----------------
// 1024 blocks x 2 waves; each wave owns 32 q-rows (2 fragments) so K/V frags
// and barriers amortize 2x. Const-sum CU mapping: 4 resident blocks' costs
// sum to 66 steps, heavy tiles dispatched first. Counted vmcnt(8).
#define KVB 64

__global__ __launch_bounds__(128) void attn_kernel(
    const bf16_t* __restrict__ Qh, const bf16_t* __restrict__ Kh,
    const bf16_t* __restrict__ VTg, unsigned short* __restrict__ Oa)
{
  const int id = blockIdx.x;                 // 0..1023
  const int xcd = id & 7;
  const int hq  = (id >> 3) & 3;
  const int s5  = id >> 5;                   // 0..31
  const int g2 = s5 >> 3, u = s5 & 7;
  int j;                                     // q-tile 0..31; cost j+1 steps
  switch (g2) {
    case 0:  j = 31 - u; break;              // dispatched first (heavy)
    case 1:  j = u;      break;
    case 2:  j = 23 - u; break;
    default: j = 8 + u;  break;              // sums: (31-u)+u+(23-u)+(8+u)=62
  }
  const int bh = xcd + 8*hq;
  const int q0 = j * 64;
  const int nkv = j + 1;

  const int tid = threadIdx.x, lane = tid & 63, w = tid >> 6;   // w 0..1
  const int r = lane & 15, g = lane >> 4;

  const bf16_t* Qp  = Qh  + (size_t)bh * Ll * DKd;
  const bf16_t* Kp  = Kh  + (size_t)bh * Ll * DKd;
  const bf16_t* VTp = VTg + (size_t)bh * Ll * DKd;   // [dk][l]

  __shared__ bf16_t Klds[2][64*64];     // 16KB, XOR-swizzled 128B rows
  __shared__ bf16_t Vlds[2][64*64];     // 16KB, V^T rows (dk), same swizzle
  __shared__ bf16_t Plds[2][2][16*64];  // 8KB, per-wave per-frag P, swizzled

  // two Q fragments per wave: rows q0 + w*32 + f*16 + r
  bf16x8 qf[2][2];
#pragma unroll
  for (int f = 0; f < 2; ++f)
#pragma unroll
    for (int ks = 0; ks < 2; ++ks)
      qf[f][ks] = *(const bf16x8*)(Qp + (size_t)(q0 + w*32 + f*16 + r)*DKd + ks*32 + g*8);

  bf16x8 ones;
#pragma unroll
  for (int jj = 0; jj < 8; ++jj) ones[jj] = (bf16_t)1.0f;

  f32x4 accO[2][4] = {};
  f32x4 accL[2] = {};
  float mrow[2] = {-1e30f, -1e30f};

  const int krow_l = lane >> 3;                        // 0..7
  const int kcol_l = ((lane & 7)*16) ^ (krow_l << 4);  // swizzled source byte
  char* Pw0 = (char*)&Plds[w][0][0];
  char* Pw1 = (char*)&Plds[w][1][0];
  const int rsw = (r & 7) << 4;
  const int b_ = bh >> 4, h_ = bh & 15;

  auto pre_tiles = [&](int kv, int buf){
#pragma unroll
    for (int i = 0; i < 4; ++i) {
      int c = i*2 + w;
      __builtin_amdgcn_global_load_lds(
        AS1C((const char*)Kp + (size_t)(kv*KVB + c*8 + krow_l)*128 + kcol_l),
        AS3((char*)&Klds[buf][0] + c*1024), 16, 0, 0);
      __builtin_amdgcn_global_load_lds(
        AS1C((const char*)VTp + (size_t)(c*8 + krow_l)*4096 + kv*128 + kcol_l),
        AS3((char*)&Vlds[buf][0] + c*1024), 16, 0, 0);
    }
  };

  pre_tiles(0, 0);

  int cur = 0;
  for (int s = 0; s < nkv; ++s) {
    if (s + 1 < nkv) {
      pre_tiles(s + 1, cur^1);   // 8 loads; this step's 8 are the oldest
      wait_vm8();
    } else {
      wait_vm0();
    }
    bar();                       // staging of [cur] visible to both waves

    // S^T = K Q^T for both frags: K frags shared -> 8 ds_reads, 16 MFMA
    const char* Kbase = (const char*)&Klds[cur][0];
    f32x4 sv[2][4] = {};
    __builtin_amdgcn_s_setprio(1);
#pragma unroll
    for (int ks = 0; ks < 2; ++ks) {
      const int kbyte = ks*64 + g*16;
#pragma unroll
      for (int n = 0; n < 4; ++n) {
        int row = n*16 + r;
        bf16x8 kf = *(const bf16x8*)(Kbase + row*128 + (kbyte ^ ((row & 7) << 4)));
        sv[0][n] = __builtin_amdgcn_mfma_f32_16x16x32_bf16(kf, qf[0][ks], sv[0][n], 0, 0, 0);
        sv[1][n] = __builtin_amdgcn_mfma_f32_16x16x32_bf16(kf, qf[1][ks], sv[1][n], 0, 0, 0);
      }
    }
    __builtin_amdgcn_s_setprio(0);

    // causal mask on the diagonal tile
    if (s == nkv - 1) {
      const int kv0 = s * KVB;
#pragma unroll
      for (int f = 0; f < 2; ++f) {
        const int qg = q0 + w*32 + f*16 + r;
#pragma unroll
        for (int n = 0; n < 4; ++n)
#pragma unroll
          for (int i = 0; i < 4; ++i)
            if (kv0 + n*16 + g*4 + i > qg) sv[f][n][i] = -1e30f;
      }
    }

    // online softmax per frag (log2 domain, defer-max), pack P -> LDS
#pragma unroll
    for (int f = 0; f < 2; ++f) {
      float m0 = fmaxf(fmaxf(sv[f][0][0], sv[f][0][1]), sv[f][0][2]);
      float m1 = fmaxf(fmaxf(sv[f][0][3], sv[f][1][0]), sv[f][1][1]);
      float m2 = fmaxf(fmaxf(sv[f][1][2], sv[f][1][3]), sv[f][2][0]);
      float m3 = fmaxf(fmaxf(sv[f][2][1], sv[f][2][2]), sv[f][2][3]);
      float m4 = fmaxf(fmaxf(sv[f][3][0], sv[f][3][1]), sv[f][3][2]);
      float mx = fmaxf(fmaxf(fmaxf(m0, m1), m2), fmaxf(fmaxf(m3, m4), sv[f][3][3]));
      if (__any(mx > mrow[f] + 8.f)) {
        mx = fmaxf(mx, __shfl_xor(mx, 16));
        mx = fmaxf(mx, __shfl_xor(mx, 32));
        float mnew = fmaxf(mrow[f], mx);
        float corr = __builtin_amdgcn_exp2f(mrow[f] - mnew);
        float c0 = __shfl(corr, g*4 + 0);
        float c1 = __shfl(corr, g*4 + 1);
        float c2 = __shfl(corr, g*4 + 2);
        float c3 = __shfl(corr, g*4 + 3);
#pragma unroll
        for (int n = 0; n < 4; ++n) {
          accO[f][n][0] *= c0; accO[f][n][1] *= c1;
          accO[f][n][2] *= c2; accO[f][n][3] *= c3;
        }
        accL[f][0] *= c0; accL[f][1] *= c1; accL[f][2] *= c2; accL[f][3] *= c3;
        mrow[f] = mnew;
      }
#pragma unroll
      for (int n = 0; n < 4; ++n)
#pragma unroll
        for (int i = 0; i < 4; ++i)
          sv[f][n][i] = __builtin_amdgcn_exp2f(sv[f][n][i] - mrow[f]);

      char* Pw = f ? Pw1 : Pw0;
#pragma unroll
      for (int n = 0; n < 4; ++n) {
        unsigned lo = (unsigned)bfu(sv[f][n][0]) | ((unsigned)bfu(sv[f][n][1]) << 16);
        unsigned hi = (unsigned)bfu(sv[f][n][2]) | ((unsigned)bfu(sv[f][n][3]) << 16);
        u32x2 pk; pk[0] = lo; pk[1] = hi;
        *(u32x2*)(Pw + r*128 + ((n*32 + g*8) ^ rsw)) = pk;
      }
    }

    // PV: V frags shared across frags -> 8 ds_reads serve 16 accO + 4 accL MFMA
    const char* Vbase = (const char*)&Vlds[cur][0];
    __builtin_amdgcn_s_setprio(1);
#pragma unroll
    for (int ks = 0; ks < 2; ++ks) {
      const int kbyte = ks*64 + g*16;
      bf16x8 pa0 = *(const bf16x8*)(Pw0 + r*128 + (kbyte ^ rsw));
      bf16x8 pa1 = *(const bf16x8*)(Pw1 + r*128 + (kbyte ^ rsw));
      accL[0] = __builtin_amdgcn_mfma_f32_16x16x32_bf16(pa0, ones, accL[0], 0, 0, 0);
      accL[1] = __builtin_amdgcn_mfma_f32_16x16x32_bf16(pa1, ones, accL[1], 0, 0, 0);
#pragma unroll
      for (int n = 0; n < 4; ++n) {
        int row = n*16 + r;
        bf16x8 vf = *(const bf16x8*)(Vbase + row*128 + (kbyte ^ ((row & 7) << 4)));
        accO[0][n] = __builtin_amdgcn_mfma_f32_16x16x32_bf16(pa0, vf, accO[0][n], 0, 0, 0);
        accO[1][n] = __builtin_amdgcn_mfma_f32_16x16x32_bf16(pa1, vf, accO[1][n], 0, 0, 0);
      }
    }
    __builtin_amdgcn_s_setprio(0);

    bar();                       // all reads of [cur] done before reuse
    cur ^= 1;
  }

  // epilogue: normalize and store both frags
#pragma unroll
  for (int f = 0; f < 2; ++f)
#pragma unroll
    for (int i = 0; i < 4; ++i) {
      float inv = 1.f / accL[f][i];
      int q = q0 + w*32 + f*16 + g*4 + i;
#pragma unroll
      for (int n = 0; n < 4; ++n)
        Oa[((size_t)(b_*Ll + q))*Dd + h_*DKd + n*16 + r] = bfu(accO[f][n][i] * inv);
    }
}

// ---------------- launch ----------------
extern "C" void kernel_launch(void* const* d_in, const int* in_sizes, int n_in,
                              void* d_out, int out_size, void* d_ws, size_t ws_size,
                              hipStream_t stream)
{
  const float* q  = (const float*)d_in[0];
  const float* k  = (const float*)d_in[1];
  const float* v  = (const float*)d_in[2];
  // d_in[3] = mask (causal, hardcoded)
  const float* wq = (const float*)d_in[4];
  const float* bq = (const float*)d_in[5];
  const float* wk = (const float*)d_in[6];
  const float* bk = (const float*)d_in[7];
  const float* wv = (const float*)d_in[8];
  const float* bv = (const float*)d_in[9];
  const float* wo = (const float*)d_in[10];
  const float* bo = (const float*)d_in[11];

  char* ws = (char*)d_ws;
  bf16_t* Xq = (bf16_t*)(ws + 0);          // dead after Q-GEMM; reused as VT
  bf16_t* Xk = (bf16_t*)(ws + 8388608);
  bf16_t* Xv = (bf16_t*)(ws + 16777216);
  bf16_t* Wq = (bf16_t*)(ws + 25165824);
  bf16_t* Wk = (bf16_t*)(ws + 27262976);
  bf16_t* Wv = (bf16_t*)(ws + 29360128);
  bf16_t* Wo = (bf16_t*)(ws + 31457280);
  bf16_t* Qh = (bf16_t*)(ws + 33554432);
  bf16_t* Kh = (bf16_t*)(ws + 41943040);
  bf16_t* Vh = (bf16_t*)(ws + 50331648);
  bf16_t* Oa = (bf16_t*)(ws + 58720256);   // total 64 MiB
  bf16_t* VT = Xq;                          // [bh][dk][l], 8MB

  const int NX4 = Mm * Dd / 4;   // 1048576
  const int NW4 = Dd * Dd / 4;   // 262144

  Cvt7 cv;
  cv.in[0]=q;  cv.out[0]=(ushort4*)Xq; cv.n4[0]=NX4;
  cv.in[1]=k;  cv.out[1]=(ushort4*)Xk; cv.n4[1]=NX4;
  cv.in[2]=v;  cv.out[2]=(ushort4*)Xv; cv.n4[2]=NX4;
  cv.in[3]=wq; cv.out[3]=(ushort4*)Wq; cv.n4[3]=NW4;
  cv.in[4]=wk; cv.out[4]=(ushort4*)Wk; cv.n4[4]=NW4;
  cv.in[5]=wv; cv.out[5]=(ushort4*)Wv; cv.n4[5]=NW4;
  cv.in[6]=wo; cv.out[6]=(ushort4*)Wo; cv.n4[6]=NW4;
  cvt_multi<<<dim3(NX4/256, 7), 256, 0, stream>>>(cv);

  const float qscale = 0.125f * 1.4426950408889634f;  // 1/sqrt(DK) * log2(e)
  GemmArgs gqkv;
  gqkv.A[0]=Xq; gqkv.A[1]=Xk; gqkv.A[2]=Xv;
  gqkv.W[0]=Wq; gqkv.W[1]=Wk; gqkv.W[2]=Wv;
  gqkv.bias[0]=bq; gqkv.bias[1]=bk; gqkv.bias[2]=bv;
  gqkv.out[0]=Qh; gqkv.out[1]=Kh; gqkv.out[2]=Vh;
  gqkv.scale[0]=qscale; gqkv.scale[1]=1.0f; gqkv.scale[2]=1.0f;
  gemm_bt<0><<<dim3(Mm/BM, Dd/BN, 3), 256, 0, stream>>>(gqkv, Mm, Dd, Dd);

  transpose_v<<<dim3(32, 32), 256, 0, stream>>>(Vh, VT);

  attn_kernel<<<dim3(1024), 128, 0, stream>>>(Qh, Kh, VT, (unsigned short*)Oa);

  GemmArgs go;
  go.A[0]=Oa; go.A[1]=Oa; go.A[2]=Oa;
  go.W[0]=Wo; go.W[1]=Wo; go.W[2]=Wo;
  go.bias[0]=bo; go.bias[1]=bo; go.bias[2]=bo;
  go.out[0]=d_out; go.out[1]=d_out; go.out[2]=d_out;
  go.scale[0]=1.0f; go.scale[1]=1.0f; go.scale[2]=1.0f;
  gemm_bt<1><<<dim3(Mm/BM, Dd/BN, 1), 256, 0, stream>>>(go, Mm, Dd, Dd);
}